// Round 10
// baseline (303.922 us; speedup 1.0000x reference)
//
#include <hip/hip_runtime.h>
#include <hip/hip_bf16.h>
#include <float.h>
#include <math.h>

#define N_NODES 50000
#define N_EDGES 400000
#define ETOT    (N_EDGES + N_NODES)   // 450000
#define F_IN    5
#define HEADS   8
#define C1      64
#define C2      32
#define C3      16
#define HC1     (HEADS * C1)          // 512
#define HC2     (HEADS * C2)          // 256
#define H2S     (HC2 + 16)            // 272 ushort = 544 B row: 256 ch + 8 f32 es
#define NEG_SLOPE 0.2f
#define NCHUNK  ((N_NODES + 255) / 256)  // 196
#define NH8     (N_NODES * HEADS)        // 400000
#define GCOLS   (HC2 + 16)            // 272: 256 h2 cols + 8 es + 8 ed
#define PACKBLK ((GCOLS * HC1) / 256) // 544 blocks for packW2X part
#define SCATBLK ((ETOT + 255) / 256)  // 1758 blocks
#define ES1BLK  ((NH8 + 255) / 256)   // 1563 blocks (also 32-node tiles)
// k_init block-range partition: [deg-pack (real edges only) | W2X | es1/ed1+xp8]
#define INIT_DEG  ((N_EDGES + 255) / 256) // 1563
#define INIT_W2X  (INIT_DEG + PACKBLK)    // 2107
#define INIT_TOT  (INIT_W2X + ES1BLK)     // 3670

// u64 degree pack: [count : bits 46..63 | weight-sum fixed-point 2^-36 : bits 0..45]
// Self-loops are NOT accumulated: scan adds +1 count / +1.0 weight analytically.
#define WFIX_SCALE 68719476736.0f      // 2^36
#define WFIX_MASK  ((1ULL << 46) - 1)

typedef short bf16x8 __attribute__((ext_vector_type(8)));
typedef float f32x4  __attribute__((ext_vector_type(4)));
typedef unsigned short ushort_t;
typedef unsigned short ushort8_t __attribute__((ext_vector_type(8)));

__device__ __forceinline__ float eluf(float x) {
    return x > 0.f ? x : (expf(x) - 1.f);
}
__device__ __forceinline__ float bf2f(unsigned short u) {
    union { unsigned int i; float f; } v; v.i = ((unsigned int)u) << 16; return v.f;
}
__device__ __forceinline__ unsigned short f2bf(float f) {
    __hip_bfloat16 b = __float2bfloat16(f);
    return *(unsigned short*)&b;
}
__device__ __forceinline__ float softnum(float es, float ed) {
    float v = es + ed;
    v = v > 0.f ? v : NEG_SLOPE * v;
    return expf(v);
}

// ------- mega-init: [deg u64-pack (real edges) | W2X pack | es1/ed1+xp8]
__global__ void k_init(const int* __restrict__ ei, const float* __restrict__ ew,
                       unsigned long long* __restrict__ pack,
                       ushort_t* __restrict__ rank,
                       const float* __restrict__ x, float* __restrict__ xp8,
                       const float* __restrict__ W2,
                       const float* __restrict__ a_src2, const float* __restrict__ a_dst2,
                       ushort_t* __restrict__ W2X,
                       const float* __restrict__ W1,
                       const float* __restrict__ a_src1, const float* __restrict__ a_dst1,
                       float* __restrict__ es, float* __restrict__ ed) {
    __shared__ float asl[HEADS * F_IN], adl[HEADS * F_IN];
    int b = blockIdx.x;
    int t = threadIdx.x;
    if (b < INIT_DEG) {
        int i = b * 256 + t;
        if (i >= N_EDGES) return;
        int d   = ei[N_EDGES + i];
        float w = ew[i];
        unsigned long long enc =
            (1ULL << 46) | (unsigned long long)(w * WFIX_SCALE + 0.5f);
        unsigned long long old = atomicAdd(&pack[d], enc);
        rank[i] = (ushort_t)(old >> 46);
    } else if (b < INIT_W2X) {
        int idx = (b - INIT_DEG) * 256 + t;
        int c = idx >> 9;       // output column 0..271
        int k = idx & 511;      // k index
        float v;
        if (c < HC2) {
            v = W2[(size_t)k * HC2 + c];
        } else {
            int h = (c - HC2) & 7;
            const float* av = (c < HC2 + 8) ? a_src2 : a_dst2;
            v = 0.f;
#pragma unroll 8
            for (int j = 0; j < C2; j++)
                v += W2[(size_t)k * HC2 + h * C2 + j] * av[h * C2 + j];
        }
        W2X[idx] = f2bf(v);
    } else {
        // es1/ed1 + xp8: fold a_src1/a_dst1 through W1 in LDS, project x.
        if (t < HEADS * F_IN) {
            int h = t / F_IN, f = t % F_IN;
            float s = 0.f, dv = 0.f;
            for (int c = 0; c < C1; c++) {
                float wv = W1[f * HC1 + h * C1 + c];
                s  += wv * a_src1[h * C1 + c];
                dv += wv * a_dst1[h * C1 + c];
            }
            asl[t] = s;
            adl[t] = dv;
        }
        __syncthreads();
        int g = (b - INIT_W2X) * 256 + t;
        if (g < NH8) {
            int n = g >> 3, h = g & 7;
            float vs = 0.f, vd = 0.f;
#pragma unroll
            for (int f = 0; f < F_IN; f++) {
                float xv = x[n * F_IN + f];
                vs += xv * asl[h * F_IN + f];
                vd += xv * adl[h * F_IN + f];
            }
            es[g] = vs;
            ed[g] = vd;
            xp8[g] = (h < F_IN) ? x[n * F_IN + h] : 0.f;
        }
    }
}

// ---- 3-kernel scan chain (R5 proven shape; R6 single-block was 137us).
// counts include the +1 analytic self-loop; dinv decodes wsum+1.
__global__ void k_scan_a(const unsigned long long* __restrict__ pack,
                         int* __restrict__ part) {
    __shared__ int lds[256];
    int t = threadIdx.x;
    int i = blockIdx.x * 256 + t;
    lds[t] = (i < N_NODES) ? (int)(pack[i] >> 46) + 1 : 0;
    __syncthreads();
    for (int off = 128; off >= 1; off >>= 1) {
        if (t < off) lds[t] += lds[t + off];
        __syncthreads();
    }
    if (t == 0) part[blockIdx.x] = lds[0];
}

__global__ void k_scan_b(int* part) {
    __shared__ int lds[256];
    int t = threadIdx.x;
    int v = (t < NCHUNK) ? part[t] : 0;
    lds[t] = v;
    __syncthreads();
    for (int off = 1; off < 256; off <<= 1) {
        int x = (t >= off) ? lds[t - off] : 0;
        __syncthreads();
        lds[t] += x;
        __syncthreads();
    }
    if (t < NCHUNK) part[t] = lds[t] - v;
}

__global__ void k_scan_c(const unsigned long long* __restrict__ pack,
                         const int* __restrict__ part,
                         int* __restrict__ offs, float* __restrict__ dinv) {
    __shared__ int lds[256];
    int t = threadIdx.x;
    int i = blockIdx.x * 256 + t;
    unsigned long long p = (i < N_NODES) ? pack[i] : 0ULL;
    int v = (i < N_NODES) ? (int)(p >> 46) + 1 : 0;
    lds[t] = v;
    __syncthreads();
    for (int off = 1; off < 256; off <<= 1) {
        int x = (t >= off) ? lds[t - off] : 0;
        __syncthreads();
        lds[t] += x;
        __syncthreads();
    }
    int excl = part[blockIdx.x] + lds[t] - v;
    if (i < N_NODES) {
        offs[i] = excl;
        float wsum = (float)(p & WFIX_MASK) * (1.0f / WFIX_SCALE) + 1.0f;
        dinv[i] = rsqrtf(wsum);                          // wsum >= 1 always
    }
    if (i == N_NODES - 1) offs[N_NODES] = excl + v;
}

// -------- scatter CSR, atomic-free ------------------------------------
__global__ void k_scatter(const int* __restrict__ ei, const int* __restrict__ offs,
                          const ushort_t* __restrict__ rank, int2* __restrict__ csr,
                          const float* __restrict__ ew, const float* __restrict__ dinv) {
    int i = blockIdx.x * 256 + threadIdx.x;
    if (i >= ETOT) return;
    int s, d, pos;
    float w;
    if (i < N_EDGES) {
        s = ei[i]; d = ei[N_EDGES + i]; w = ew[i];
        pos = offs[d] + (int)rank[i];
    } else {
        s = d = i - N_EDGES; w = 1.f;
        pos = offs[d + 1] - 1;
    }
    float nrm = dinv[s] * w * dinv[d];
    csr[pos] = make_int2(s, __float_as_int(nrm));
}

// -------- layer-1 aggregation walk (4-edge batch, proven shape) --------
// Writes aggx[f*NH8+g] (8MB) -- the x2 expansion moved into k_expgemm.
// Walk stays a lean high-occupancy kernel (R8 lesson: don't burden it).
__global__ void k_agg(const float* __restrict__ xp8,
                      const float* __restrict__ es1, const float* __restrict__ ed1,
                      const int* __restrict__ offs, const int2* __restrict__ csr,
                      float* __restrict__ aggx) {
    int g = blockIdx.x * blockDim.x + threadIdx.x;
    if (g >= NH8) return;
    int d = g >> 3, h = g & 7;
    float edv = ed1[g];
    int k0 = offs[d], k1 = offs[d + 1];
    float a0 = 0.f, a1 = 0.f, a2 = 0.f, a3 = 0.f, a4 = 0.f, exsum = 0.f;
    int k = k0;
    for (; k + 3 < k1; k += 4) {
        int2 c0 = csr[k], c1 = csr[k + 1], c2 = csr[k + 2], c3 = csr[k + 3];
        float r0 = es1[c0.x * HEADS + h];
        float r1 = es1[c1.x * HEADS + h];
        float r2 = es1[c2.x * HEADS + h];
        float r3 = es1[c3.x * HEADS + h];
        float4 A0 = *(const float4*)(xp8 + (size_t)c0.x * 8);
        float  B0 = xp8[(size_t)c0.x * 8 + 4];
        float4 A1 = *(const float4*)(xp8 + (size_t)c1.x * 8);
        float  B1 = xp8[(size_t)c1.x * 8 + 4];
        float4 A2 = *(const float4*)(xp8 + (size_t)c2.x * 8);
        float  B2 = xp8[(size_t)c2.x * 8 + 4];
        float4 A3 = *(const float4*)(xp8 + (size_t)c3.x * 8);
        float  B3 = xp8[(size_t)c3.x * 8 + 4];
        float x0 = softnum(r0, edv);
        float x1 = softnum(r1, edv);
        float x2 = softnum(r2, edv);
        float x3 = softnum(r3, edv);
        a0 += x0 * A0.x + x1 * A1.x + x2 * A2.x + x3 * A3.x;
        a1 += x0 * A0.y + x1 * A1.y + x2 * A2.y + x3 * A3.y;
        a2 += x0 * A0.z + x1 * A1.z + x2 * A2.z + x3 * A3.z;
        a3 += x0 * A0.w + x1 * A1.w + x2 * A2.w + x3 * A3.w;
        a4 += x0 * B0   + x1 * B1   + x2 * B2   + x3 * B3;
        exsum += (x0 + x1) + (x2 + x3);
    }
    for (; k < k1; k++) {
        int2 c0 = csr[k];
        float x0 = softnum(es1[c0.x * HEADS + h], edv);
        float4 A0 = *(const float4*)(xp8 + (size_t)c0.x * 8);
        float  B0 = xp8[(size_t)c0.x * 8 + 4];
        a0 += x0 * A0.x;
        a1 += x0 * A0.y;
        a2 += x0 * A0.z;
        a3 += x0 * A0.w;
        a4 += x0 * B0;
        exsum += x0;
    }
    float inv = 1.f / (exsum + 1e-16f);
    aggx[0 * NH8 + g] = a0 * inv;
    aggx[1 * NH8 + g] = a1 * inv;
    aggx[2 * NH8 + g] = a2 * inv;
    aggx[3 * NH8 + g] = a3 * inv;
    aggx[4 * NH8 + g] = a4 * inv;
}

// -------- fused expand + MFMA GEMM (kills the 102MB x2 round-trip) -----
// Phase A: 32 nodes' x2 rows = elu(aggx@W1 + b1) -> bf16 in LDS (XOR-
// swizzled cols: elem ^= (row&7)<<3 breaks the 1KB-stride bank alias).
// Phase B: known-good MFMA loop retiled to 32 rows: 4 waves = 2 row-
// groups x 2 col-halves (tiles 0-8 / 9-16), acc[9]; Bs staging+prefetch
// verbatim from the proven k_gemm_mfma. LDS 49.8KB -> 3 blocks/CU =
// 12 waves/CU, same occupancy as the old (256,3) gemm.
__global__ __launch_bounds__(256, 3) void k_expgemm(const float* __restrict__ aggx,
                                                    const float* __restrict__ W1,
                                                    const float* __restrict__ b1,
                                                    const short* __restrict__ W2X,
                                                    ushort_t* __restrict__ h2x,
                                                    float* __restrict__ ed2) {
    __shared__ short xs2[32 * HC1];    // 32 KB
    __shared__ short Bs[GCOLS * 32];   // 17.4 KB
    int t = threadIdx.x;

    // ---- Phase A: expand into LDS ----
    {
        int wave = t >> 6, j = t & 63;
        int h = j >> 3;
        const float* w1p = W1 + j * 8;
#pragma unroll 1
        for (int it = 0; it < 8; ++it) {
            int nl = wave * 8 + it;
            int n = blockIdx.x * 32 + nl;
            ushort8_t o;
            if (n < N_NODES) {
                int g = n * HEADS + h;
                float av[F_IN];
#pragma unroll
                for (int f = 0; f < F_IN; f++) av[f] = aggx[f * NH8 + g];
                float4 s0 = *(const float4*)(b1 + j * 8);
                float4 s1 = *(const float4*)(b1 + j * 8 + 4);
#pragma unroll
                for (int f = 0; f < F_IN; f++) {
                    float4 w0  = *(const float4*)(w1p + f * HC1);
                    float4 w1v = *(const float4*)(w1p + f * HC1 + 4);
                    s0.x += av[f] * w0.x;  s0.y += av[f] * w0.y;
                    s0.z += av[f] * w0.z;  s0.w += av[f] * w0.w;
                    s1.x += av[f] * w1v.x; s1.y += av[f] * w1v.y;
                    s1.z += av[f] * w1v.z; s1.w += av[f] * w1v.w;
                }
                o[0] = f2bf(eluf(s0.x)); o[1] = f2bf(eluf(s0.y));
                o[2] = f2bf(eluf(s0.z)); o[3] = f2bf(eluf(s0.w));
                o[4] = f2bf(eluf(s1.x)); o[5] = f2bf(eluf(s1.y));
                o[6] = f2bf(eluf(s1.z)); o[7] = f2bf(eluf(s1.w));
            } else {
                for (int q = 0; q < 8; q++) o[q] = 0;
            }
            int scol = (j * 8) ^ ((nl & 7) << 3);
            *(ushort8_t*)(xs2 + nl * HC1 + scol) = *(ushort8_t*)&o;
        }
    }
    __syncthreads();

    // ---- Phase B: 32-row MFMA GEMM ----
    int wave = t >> 6;
    int lane = t & 63;
    int lo   = lane & 15;
    int quad = lane >> 4;
    int rg   = (wave & 1) * 16;        // row group
    int half = wave >> 1;              // col half
    int f0   = half ? 9 : 0;
    int nf   = half ? 8 : 9;

    f32x4 acc[9];
#pragma unroll
    for (int f = 0; f < 9; f++) acc[f] = (f32x4){0.f, 0.f, 0.f, 0.f};

    // stage tile k0=0
    for (int idx = t; idx < GCOLS * 4; idx += 256) {
        int c = idx >> 2, q = idx & 3;
        int s = (q + c + (c >> 2)) & 3;
        *(bf16x8*)(Bs + c * 32 + s * 8) = *(const bf16x8*)(W2X + (size_t)c * HC1 + q * 8);
    }
    __syncthreads();

#pragma unroll 1
    for (int k0 = 0; k0 < HC1; k0 += 32) {
        int nk = k0 + 32;
        bf16x8 pre[5];
        if (nk < HC1) {
#pragma unroll
            for (int j = 0; j < 5; j++) {
                int idx = t + j * 256;
                if (idx < GCOLS * 4) {
                    int c = idx >> 2, q = idx & 3;
                    pre[j] = *(const bf16x8*)(W2X + (size_t)c * HC1 + nk + q * 8);
                }
            }
        }
        int arow = rg + lo;
        int aelem = (k0 + quad * 8) ^ ((arow & 7) << 3);
        bf16x8 aF = *(const bf16x8*)(xs2 + arow * HC1 + aelem);
#pragma unroll
        for (int f = 0; f < 9; f++) {
            if (f < nf) {
                int c = (f0 + f) * 16 + lo;
                int s = (quad + c + (c >> 2)) & 3;
                bf16x8 bF = *(const bf16x8*)(Bs + c * 32 + s * 8);
                acc[f] = __builtin_amdgcn_mfma_f32_16x16x32_bf16(aF, bF, acc[f], 0, 0, 0);
            }
        }
        __syncthreads();
        if (nk < HC1) {
#pragma unroll
            for (int j = 0; j < 5; j++) {
                int idx = t + j * 256;
                if (idx < GCOLS * 4) {
                    int c = idx >> 2, q = idx & 3;
                    int s = (q + c + (c >> 2)) & 3;
                    *(bf16x8*)(Bs + c * 32 + s * 8) = pre[j];
                }
            }
            __syncthreads();
        }
    }

    int rowb = blockIdx.x * 32 + rg + quad * 4;
#pragma unroll
    for (int f = 0; f < 9; f++) {
        if (f < nf) {
            int af = f0 + f;
            if (af < 16) {
#pragma unroll
                for (int r = 0; r < 4; r++) {
                    int row = rowb + r;
                    if (row < N_NODES)
                        h2x[(size_t)row * H2S + af * 16 + lo] = f2bf(acc[f][r]);
                }
            } else {
#pragma unroll
                for (int r = 0; r < 4; r++) {
                    int row = rowb + r;
                    if (row < N_NODES) {
                        if (lo < 8) *(float*)(h2x + (size_t)row * H2S + HC2 + 2 * lo) = acc[f][r];
                        else        ed2[row * HEADS + (lo - 8)] = acc[f][r];
                    }
                }
            }
        }
    }
}

// -------- layer-2 GAT agg: at gather-service floor (control) -----------
// R8's hg fusion regressed 46->130us (serial shuffle chain); do not fuse.
__global__ __launch_bounds__(128) void k_gat_agg2(const ushort_t* __restrict__ h2x,
                                                  const float* __restrict__ ed2,
                                                  const int* __restrict__ offs,
                                                  const int2* __restrict__ csr,
                                                  const float* __restrict__ b2,
                                                  ushort_t* __restrict__ x3bf) {
    int wave = threadIdx.x >> 6;
    int lane = threadIdx.x & 63;
    int d = blockIdx.x * 2 + wave;
    if (d >= N_NODES) return;
    int c4 = lane * 4;            // 4 channels per lane
    int h  = lane >> 3;           // head = c4/32
    float edv = ed2[d * HEADS + h];
    int k0 = offs[d], k1 = offs[d + 1];
    float acc0 = 0.f, acc1 = 0.f, acc2 = 0.f, acc3 = 0.f, exsum = 0.f;
    int k = k0;
    for (; k + 3 < k1; k += 4) {
        int2 e0 = csr[k], e1 = csr[k + 1], e2 = csr[k + 2], e3 = csr[k + 3];
        const ushort_t* p0 = h2x + (size_t)e0.x * H2S;
        const ushort_t* p1 = h2x + (size_t)e1.x * H2S;
        const ushort_t* p2 = h2x + (size_t)e2.x * H2S;
        const ushort_t* p3 = h2x + (size_t)e3.x * H2S;
        float r0 = *(const float*)(p0 + HC2 + 2 * h);
        float r1 = *(const float*)(p1 + HC2 + 2 * h);
        float r2 = *(const float*)(p2 + HC2 + 2 * h);
        float r3 = *(const float*)(p3 + HC2 + 2 * h);
        ushort4 v0 = *(const ushort4*)(p0 + c4);
        ushort4 v1 = *(const ushort4*)(p1 + c4);
        ushort4 v2 = *(const ushort4*)(p2 + c4);
        ushort4 v3 = *(const ushort4*)(p3 + c4);
        float x0 = softnum(r0, edv);
        float x1 = softnum(r1, edv);
        float x2 = softnum(r2, edv);
        float x3 = softnum(r3, edv);
        acc0 += x0 * bf2f(v0.x) + x1 * bf2f(v1.x) + x2 * bf2f(v2.x) + x3 * bf2f(v3.x);
        acc1 += x0 * bf2f(v0.y) + x1 * bf2f(v1.y) + x2 * bf2f(v2.y) + x3 * bf2f(v3.y);
        acc2 += x0 * bf2f(v0.z) + x1 * bf2f(v1.z) + x2 * bf2f(v2.z) + x3 * bf2f(v3.z);
        acc3 += x0 * bf2f(v0.w) + x1 * bf2f(v1.w) + x2 * bf2f(v2.w) + x3 * bf2f(v3.w);
        exsum += (x0 + x1) + (x2 + x3);
    }
    for (; k < k1; k++) {
        int2 e0 = csr[k];
        const ushort_t* p0 = h2x + (size_t)e0.x * H2S;
        float x0 = softnum(*(const float*)(p0 + HC2 + 2 * h), edv);
        ushort4 v0 = *(const ushort4*)(p0 + c4);
        acc0 += x0 * bf2f(v0.x);
        acc1 += x0 * bf2f(v0.y);
        acc2 += x0 * bf2f(v0.z);
        acc3 += x0 * bf2f(v0.w);
        exsum += x0;
    }
    float inv = 1.f / (exsum + 1e-16f);
    float4 bias = *(const float4*)(b2 + c4);
    ushort4 o;
    o.x = f2bf(eluf(acc0 * inv + bias.x));
    o.y = f2bf(eluf(acc1 * inv + bias.y));
    o.z = f2bf(eluf(acc2 * inv + bias.z));
    o.w = f2bf(eluf(acc3 * inv + bias.w));
    *(ushort4*)(x3bf + (size_t)d * HC2 + c4) = o;
}

// ---------------- hg = x3 @ Wg  (N,256)@(256,16), bf16 x3 --------------
__global__ __launch_bounds__(256) void k_hg(const ushort_t* __restrict__ x3bf,
                                            const float* __restrict__ Wg,
                                            float* __restrict__ hg) {
    __shared__ float xs[16 * 260];
    int n0 = blockIdx.x * 16;
    int t  = threadIdx.x;
    for (int q = t; q < 16 * HC2 / 4; q += 256) {
        int r  = q >> 6;           // row within tile (64 ushort4 per row)
        int cc = (q & 63) * 4;
        int n  = n0 + r;
        ushort4 v = make_ushort4(0, 0, 0, 0);
        if (n < N_NODES) v = *(const ushort4*)(x3bf + (size_t)n * HC2 + cc);
        xs[r * 260 + cc + 0] = bf2f(v.x);
        xs[r * 260 + cc + 1] = bf2f(v.y);
        xs[r * 260 + cc + 2] = bf2f(v.z);
        xs[r * 260 + cc + 3] = bf2f(v.w);
    }
    __syncthreads();
    int r = t >> 4, c = t & 15;
    const float* xr = xs + r * 260;
    float acc = 0.f;
#pragma unroll 8
    for (int k = 0; k < HC2; k += 4) {
        float4 v = *(const float4*)(xr + k);
        acc += v.x * Wg[(k + 0) * C3 + c];
        acc += v.y * Wg[(k + 1) * C3 + c];
        acc += v.z * Wg[(k + 2) * C3 + c];
        acc += v.w * Wg[(k + 3) * C3 + c];
    }
    int n = n0 + r;
    if (n < N_NODES) hg[(size_t)n * C3 + c] = acc;
}

// ---------------- GCN aggregate + ELU + FC + sigmoid (fused) -----------
__global__ __launch_bounds__(256) void k_gcn_out(const float* __restrict__ hg,
                                                 const int* __restrict__ offs,
                                                 const int2* __restrict__ csr,
                                                 const float* __restrict__ bg,
                                                 const float* __restrict__ Wfc,
                                                 const float* __restrict__ bfc,
                                                 float* __restrict__ out) {
    int t = threadIdx.x;
    int r = t >> 4, c = t & 15;
    int d = blockIdx.x * 16 + r;
    float val = 0.f;
    if (d < N_NODES) {
        int k0 = offs[d], k1 = offs[d + 1];
        float acc = 0.f;
        int k = k0;
        for (; k + 3 < k1; k += 4) {
            int2 e0 = csr[k], e1 = csr[k + 1], e2 = csr[k + 2], e3 = csr[k + 3];
            float g0 = hg[(size_t)e0.x * C3 + c];
            float g1 = hg[(size_t)e1.x * C3 + c];
            float g2 = hg[(size_t)e2.x * C3 + c];
            float g3 = hg[(size_t)e3.x * C3 + c];
            acc += g0 * __int_as_float(e0.y) + g1 * __int_as_float(e1.y)
                 + g2 * __int_as_float(e2.y) + g3 * __int_as_float(e3.y);
        }
        for (; k < k1; k++) {
            int2 e0 = csr[k];
            acc += hg[(size_t)e0.x * C3 + c] * __int_as_float(e0.y);
        }
        val = eluf(acc + bg[c]);
    }
    float z = val * Wfc[c];
#pragma unroll
    for (int off = 8; off >= 1; off >>= 1) z += __shfl_xor(z, off, 16);
    if (c == 0 && d < N_NODES) out[d] = 1.f / (1.f + expf(-(z + bfc[0])));
}

// =======================================================================
extern "C" void kernel_launch(void* const* d_in, const int* in_sizes, int n_in,
                              void* d_out, int out_size, void* d_ws, size_t ws_size,
                              hipStream_t stream) {
    const float* x       = (const float*)d_in[0];
    const int*   ei      = (const int*)  d_in[1];
    const float* ew      = (const float*)d_in[2];
    const float* W1      = (const float*)d_in[3];
    const float* a_src1  = (const float*)d_in[4];
    const float* a_dst1  = (const float*)d_in[5];
    const float* b1      = (const float*)d_in[6];
    const float* W2      = (const float*)d_in[7];
    const float* a_src2  = (const float*)d_in[8];
    const float* a_dst2  = (const float*)d_in[9];
    const float* b2      = (const float*)d_in[10];
    const float* Wg      = (const float*)d_in[11];
    const float* bg      = (const float*)d_in[12];
    const float* Wfc     = (const float*)d_in[13];
    const float* bfc     = (const float*)d_in[14];
    float* out = (float*)d_out;

    char* w = (char*)d_ws;
    size_t off = 0;
    auto alloc = [&](size_t bytes) -> void* {
        void* p = w + off;
        off = (off + bytes + 255) & ~(size_t)255;
        return p;
    };
    ushort_t* W2X  = (ushort_t*)alloc((size_t)GCOLS * HC1 * 2);
    ushort_t* h2x  = (ushort_t*)alloc((size_t)N_NODES * H2S * 2);
    ushort_t* x3bf = (ushort_t*)alloc((size_t)N_NODES * HC2 * 2);
    float* hg     = (float*)alloc((size_t)N_NODES * C3 * 4);
    float* aggx   = (float*)alloc((size_t)F_IN * NH8 * 4);
    float* es1    = (float*)alloc((size_t)NH8 * 4);
    float* ed1    = (float*)alloc((size_t)NH8 * 4);
    float* ed2    = (float*)alloc((size_t)NH8 * 4);
    // zero-init region: just the u64 degree pack
    unsigned long long* pack = (unsigned long long*)alloc((size_t)N_NODES * 8);
    char*  zero_end = w + off;
    ushort_t* rank = (ushort_t*)alloc((size_t)N_EDGES * 2);
    int*   offs   = (int*)  alloc((size_t)(N_NODES + 1) * 4);
    int*   part   = (int*)  alloc(256 * 4);
    int2*  csr    = (int2*) alloc((size_t)ETOT * 8);
    float* dinv   = (float*)alloc((size_t)N_NODES * 4);
    float* xp8    = (float*)alloc((size_t)N_NODES * 8 * 4);

    // ---- CSR build + init + weight prep ----
    hipMemsetAsync(pack, 0, (size_t)(zero_end - (char*)pack), stream);
    k_init<<<dim3(INIT_TOT), dim3(256), 0, stream>>>(
        ei, ew, pack, rank, x, xp8, W2, a_src2, a_dst2, W2X,
        W1, a_src1, a_dst1, es1, ed1);
    k_scan_a<<<dim3(NCHUNK), dim3(256), 0, stream>>>(pack, part);
    k_scan_b<<<dim3(1), dim3(256), 0, stream>>>(part);
    k_scan_c<<<dim3(NCHUNK), dim3(256), 0, stream>>>(pack, part, offs, dinv);
    k_scatter<<<dim3(SCATBLK), dim3(256), 0, stream>>>(ei, offs, rank, csr, ew, dinv);

    // ---- GAT layer 1 (walk -> aggx; expand fused into the GEMM) ----
    k_agg<<<dim3(ES1BLK), dim3(256), 0, stream>>>(xp8, es1, ed1, offs, csr, aggx);
    k_expgemm<<<dim3(ES1BLK), dim3(256), 0, stream>>>(
        aggx, W1, b1, (const short*)W2X, h2x, ed2);

    // ---- GAT layer 2 aggregation ----
    k_gat_agg2<<<dim3((N_NODES + 1) / 2), dim3(128), 0, stream>>>(
        h2x, ed2, offs, csr, b2, x3bf);

    // ---- GCN + FC + sigmoid ----
    k_hg<<<dim3((N_NODES + 15) / 16), dim3(256), 0, stream>>>(x3bf, Wg, hg);
    k_gcn_out<<<dim3((N_NODES + 15) / 16), dim3(256), 0, stream>>>(
        hg, offs, csr, bg, Wfc, bfc, out);
}

// Round 11
// 275.705 us; speedup vs baseline: 1.1023x; 1.1023x over previous
//
#include <hip/hip_runtime.h>
#include <hip/hip_bf16.h>
#include <float.h>
#include <math.h>

#define N_NODES 50000
#define N_EDGES 400000
#define ETOT    (N_EDGES + N_NODES)   // 450000
#define F_IN    5
#define HEADS   8
#define C1      64
#define C2      32
#define C3      16
#define HC1     (HEADS * C1)          // 512
#define HC2     (HEADS * C2)          // 256
#define H2S     (HC2 + 16)            // 272 ushort = 544 B row: 256 ch + 8 f32 es
#define NEG_SLOPE 0.2f
#define NCHUNK  ((N_NODES + 255) / 256)  // 196
#define NH8     (N_NODES * HEADS)        // 400000
#define MPAD    (((N_NODES + 63) / 64) * 64)  // 50048 rows for MFMA GEMM
#define GCOLS   (HC2 + 16)            // 272: 256 h2 cols + 8 es + 8 ed
#define PACKBLK ((GCOLS * HC1) / 256) // 544 blocks for packW2X part
#define SCATBLK ((ETOT + 255) / 256)  // 1758 blocks
#define ES1BLK  ((NH8 + 255) / 256)   // 1563 blocks for es1 part
// k_init block-range partition: [deg-pack (real edges only) | W2X | es1/ed1+xp8]
#define INIT_DEG  ((N_EDGES + 255) / 256) // 1563
#define INIT_W2X  (INIT_DEG + PACKBLK)    // 2107
#define INIT_TOT  (INIT_W2X + ES1BLK)     // 3670

// u64 degree pack: [count : bits 46..63 | weight-sum fixed-point 2^-36 : bits 0..45]
// Self-loops are NOT accumulated: scan adds +1 count / +1.0 weight analytically.
#define WFIX_SCALE 68719476736.0f      // 2^36
#define WFIX_MASK  ((1ULL << 46) - 1)

typedef short bf16x8 __attribute__((ext_vector_type(8)));
typedef float f32x4  __attribute__((ext_vector_type(4)));
typedef unsigned short ushort_t;
typedef unsigned short ushort8_t __attribute__((ext_vector_type(8)));

__device__ __forceinline__ float eluf(float x) {
    return x > 0.f ? x : (expf(x) - 1.f);
}
__device__ __forceinline__ float bf2f(unsigned short u) {
    union { unsigned int i; float f; } v; v.i = ((unsigned int)u) << 16; return v.f;
}
__device__ __forceinline__ unsigned short f2bf(float f) {
    __hip_bfloat16 b = __float2bfloat16(f);
    return *(unsigned short*)&b;
}
__device__ __forceinline__ float softnum(float es, float ed) {
    float v = es + ed;
    v = v > 0.f ? v : NEG_SLOPE * v;
    return expf(v);
}

// ------- mega-init: [deg u64-pack (real edges) | W2X pack | es1/ed1+xp8]
__global__ void k_init(const int* __restrict__ ei, const float* __restrict__ ew,
                       unsigned long long* __restrict__ pack,
                       ushort_t* __restrict__ rank,
                       const float* __restrict__ x, float* __restrict__ xp8,
                       const float* __restrict__ W2,
                       const float* __restrict__ a_src2, const float* __restrict__ a_dst2,
                       ushort_t* __restrict__ W2X,
                       const float* __restrict__ W1,
                       const float* __restrict__ a_src1, const float* __restrict__ a_dst1,
                       float* __restrict__ es, float* __restrict__ ed) {
    __shared__ float asl[HEADS * F_IN], adl[HEADS * F_IN];
    int b = blockIdx.x;
    int t = threadIdx.x;
    if (b < INIT_DEG) {
        int i = b * 256 + t;
        if (i >= N_EDGES) return;
        int d   = ei[N_EDGES + i];
        float w = ew[i];
        unsigned long long enc =
            (1ULL << 46) | (unsigned long long)(w * WFIX_SCALE + 0.5f);
        unsigned long long old = atomicAdd(&pack[d], enc);
        rank[i] = (ushort_t)(old >> 46);
    } else if (b < INIT_W2X) {
        int idx = (b - INIT_DEG) * 256 + t;
        int c = idx >> 9;       // output column 0..271
        int k = idx & 511;      // k index
        float v;
        if (c < HC2) {
            v = W2[(size_t)k * HC2 + c];
        } else {
            int h = (c - HC2) & 7;
            const float* av = (c < HC2 + 8) ? a_src2 : a_dst2;
            v = 0.f;
#pragma unroll 8
            for (int j = 0; j < C2; j++)
                v += W2[(size_t)k * HC2 + h * C2 + j] * av[h * C2 + j];
        }
        W2X[idx] = f2bf(v);
    } else {
        // es1/ed1 + xp8: fold a_src1/a_dst1 through W1 in LDS, project x.
        if (t < HEADS * F_IN) {
            int h = t / F_IN, f = t % F_IN;
            float s = 0.f, dv = 0.f;
            for (int c = 0; c < C1; c++) {
                float wv = W1[f * HC1 + h * C1 + c];
                s  += wv * a_src1[h * C1 + c];
                dv += wv * a_dst1[h * C1 + c];
            }
            asl[t] = s;
            adl[t] = dv;
        }
        __syncthreads();
        int g = (b - INIT_W2X) * 256 + t;
        if (g < NH8) {
            int n = g >> 3, h = g & 7;
            float vs = 0.f, vd = 0.f;
#pragma unroll
            for (int f = 0; f < F_IN; f++) {
                float xv = x[n * F_IN + f];
                vs += xv * asl[h * F_IN + f];
                vd += xv * adl[h * F_IN + f];
            }
            es[g] = vs;
            ed[g] = vd;
            xp8[g] = (h < F_IN) ? x[n * F_IN + h] : 0.f;
        }
    }
}

// ---- scan chain (R5 proven shape), scan_b folded into scan_c ----------
// scan_a: per-256-chunk totals (counts include the +1 analytic self-loop).
__global__ void k_scan_a(const unsigned long long* __restrict__ pack,
                         int* __restrict__ part) {
    __shared__ int lds[256];
    int t = threadIdx.x;
    int i = blockIdx.x * 256 + t;
    lds[t] = (i < N_NODES) ? (int)(pack[i] >> 46) + 1 : 0;
    __syncthreads();
    for (int off = 128; off >= 1; off >>= 1) {
        if (t < off) lds[t] += lds[t + off];
        __syncthreads();
    }
    if (t == 0) part[blockIdx.x] = lds[0];
}

// scan_c: computes its own base from the raw part[] totals in-LDS
// (196 adds; replaces the separate scan_b launch), then the per-element
// exclusive scan + dinv decode (wsum+1, always >= 1).
__global__ void k_scan_c(const unsigned long long* __restrict__ pack,
                         const int* __restrict__ part,
                         int* __restrict__ offs, float* __restrict__ dinv) {
    __shared__ int lds[256];
    __shared__ int base_s;
    int t = threadIdx.x;
    // base = sum part[0..blockIdx.x)
    lds[t] = (t < NCHUNK && t < blockIdx.x) ? part[t] : 0;
    __syncthreads();
    for (int off = 128; off >= 1; off >>= 1) {
        if (t < off) lds[t] += lds[t + off];
        __syncthreads();
    }
    if (t == 0) base_s = lds[0];
    __syncthreads();
    int base = base_s;
    __syncthreads();
    int i = blockIdx.x * 256 + t;
    unsigned long long p = (i < N_NODES) ? pack[i] : 0ULL;
    int v = (i < N_NODES) ? (int)(p >> 46) + 1 : 0;
    lds[t] = v;
    __syncthreads();
    for (int off = 1; off < 256; off <<= 1) {
        int x = (t >= off) ? lds[t - off] : 0;
        __syncthreads();
        lds[t] += x;
        __syncthreads();
    }
    int excl = base + lds[t] - v;
    if (i < N_NODES) {
        offs[i] = excl;
        float wsum = (float)(p & WFIX_MASK) * (1.0f / WFIX_SCALE) + 1.0f;
        dinv[i] = rsqrtf(wsum);
    }
    if (i == N_NODES - 1) offs[N_NODES] = excl + v;
}

// -------- scatter CSR, atomic-free ------------------------------------
// Real edge: pos = offs[d] + rank[i]. Self-loop: pos = offs[d+1]-1.
// csr.y = precomputed GCN norm (bitcast float) = dinv[s]*w*dinv[d].
__global__ void k_scatter(const int* __restrict__ ei, const int* __restrict__ offs,
                          const ushort_t* __restrict__ rank, int2* __restrict__ csr,
                          const float* __restrict__ ew, const float* __restrict__ dinv) {
    int i = blockIdx.x * 256 + threadIdx.x;
    if (i >= ETOT) return;
    int s, d, pos;
    float w;
    if (i < N_EDGES) {
        s = ei[i]; d = ei[N_EDGES + i]; w = ew[i];
        pos = offs[d] + (int)rank[i];
    } else {
        s = d = i - N_EDGES; w = 1.f;
        pos = offs[d + 1] - 1;
    }
    float nrm = dinv[s] * w * dinv[d];
    csr[pos] = make_int2(s, __float_as_int(nrm));
}

// -------- fused layer-1: aggregation (4-edge batch) + expand via LDS ---
// R9 known-good. (R10's expand->GEMM fusion regressed: 2 blocks/CU,
// serialized phases, 91us. Fusion rule: only fuse into existing stalls.)
__global__ __launch_bounds__(256) void k_aggexp(const float* __restrict__ xp8,
                                                const float* __restrict__ es1,
                                                const float* __restrict__ ed1,
                                                const int* __restrict__ offs,
                                                const int2* __restrict__ csr,
                                                const float* __restrict__ W1,
                                                const float* __restrict__ b1,
                                                ushort_t* __restrict__ x2bf) {
    __shared__ float ax[256 * F_IN];   // [t*5+f]: node-local x-aggregate
    int t = threadIdx.x;
    int g = blockIdx.x * 256 + t;
    if (g < NH8) {
        int d = g >> 3, h = g & 7;
        float edv = ed1[g];
        int k0 = offs[d], k1 = offs[d + 1];
        float a0 = 0.f, a1 = 0.f, a2 = 0.f, a3 = 0.f, a4 = 0.f, exsum = 0.f;
        int k = k0;
        for (; k + 3 < k1; k += 4) {
            int2 c0 = csr[k], c1 = csr[k + 1], c2 = csr[k + 2], c3 = csr[k + 3];
            float r0 = es1[c0.x * HEADS + h];
            float r1 = es1[c1.x * HEADS + h];
            float r2 = es1[c2.x * HEADS + h];
            float r3 = es1[c3.x * HEADS + h];
            float4 A0 = *(const float4*)(xp8 + (size_t)c0.x * 8);
            float  B0 = xp8[(size_t)c0.x * 8 + 4];
            float4 A1 = *(const float4*)(xp8 + (size_t)c1.x * 8);
            float  B1 = xp8[(size_t)c1.x * 8 + 4];
            float4 A2 = *(const float4*)(xp8 + (size_t)c2.x * 8);
            float  B2 = xp8[(size_t)c2.x * 8 + 4];
            float4 A3 = *(const float4*)(xp8 + (size_t)c3.x * 8);
            float  B3 = xp8[(size_t)c3.x * 8 + 4];
            float x0 = softnum(r0, edv);
            float x1 = softnum(r1, edv);
            float x2 = softnum(r2, edv);
            float x3 = softnum(r3, edv);
            a0 += x0 * A0.x + x1 * A1.x + x2 * A2.x + x3 * A3.x;
            a1 += x0 * A0.y + x1 * A1.y + x2 * A2.y + x3 * A3.y;
            a2 += x0 * A0.z + x1 * A1.z + x2 * A2.z + x3 * A3.z;
            a3 += x0 * A0.w + x1 * A1.w + x2 * A2.w + x3 * A3.w;
            a4 += x0 * B0   + x1 * B1   + x2 * B2   + x3 * B3;
            exsum += (x0 + x1) + (x2 + x3);
        }
        for (; k < k1; k++) {
            int2 c0 = csr[k];
            float x0 = softnum(es1[c0.x * HEADS + h], edv);
            float4 A0 = *(const float4*)(xp8 + (size_t)c0.x * 8);
            float  B0 = xp8[(size_t)c0.x * 8 + 4];
            a0 += x0 * A0.x;
            a1 += x0 * A0.y;
            a2 += x0 * A0.z;
            a3 += x0 * A0.w;
            a4 += x0 * B0;
            exsum += x0;
        }
        float inv = 1.f / (exsum + 1e-16f);
        float* ap = ax + t * F_IN;
        ap[0] = a0 * inv;
        ap[1] = a1 * inv;
        ap[2] = a2 * inv;
        ap[3] = a3 * inv;
        ap[4] = a4 * inv;
    }
    __syncthreads();
    // expand: one wave per node, 8 nodes per wave sequentially.
    int wave = t >> 6, j = t & 63;
    int n0 = blockIdx.x * 32;
    int h = j >> 3;
    const float* w1p = W1 + j * 8;
#pragma unroll 1
    for (int it = 0; it < 8; ++it) {
        int nl = wave * 8 + it;
        int n = n0 + nl;
        if (n >= N_NODES) break;
        const float* ap = ax + (nl * 8 + h) * F_IN;
        float av[F_IN];
#pragma unroll
        for (int f = 0; f < F_IN; f++) av[f] = ap[f];
        float4 s0 = *(const float4*)(b1 + j * 8);
        float4 s1 = *(const float4*)(b1 + j * 8 + 4);
#pragma unroll
        for (int f = 0; f < F_IN; f++) {
            float4 w0  = *(const float4*)(w1p + f * HC1);
            float4 w1v = *(const float4*)(w1p + f * HC1 + 4);
            s0.x += av[f] * w0.x;  s0.y += av[f] * w0.y;
            s0.z += av[f] * w0.z;  s0.w += av[f] * w0.w;
            s1.x += av[f] * w1v.x; s1.y += av[f] * w1v.y;
            s1.z += av[f] * w1v.z; s1.w += av[f] * w1v.w;
        }
        ushort8_t o;
        o[0] = f2bf(eluf(s0.x)); o[1] = f2bf(eluf(s0.y));
        o[2] = f2bf(eluf(s0.z)); o[3] = f2bf(eluf(s0.w));
        o[4] = f2bf(eluf(s1.x)); o[5] = f2bf(eluf(s1.y));
        o[6] = f2bf(eluf(s1.z)); o[7] = f2bf(eluf(s1.w));
        *(ushort8_t*)(x2bf + (size_t)n * HC1 + j * 8) = o;
    }
}

// ------ bf16 MFMA GEMM (known-good core) -------------------------------
// h2 rows stride H2S=272 ushorts (544 B): 256 bf16 ch + 8 f32 es.
__global__ __launch_bounds__(256, 3) void k_gemm_mfma(const short* __restrict__ A,
                                                      const short* __restrict__ W2X,
                                                      ushort_t* __restrict__ h2x,
                                                      float* __restrict__ ed2) {
    __shared__ short Bs[GCOLS * 32];   // 272 cols * 64 B = 17408 B
    int t    = threadIdx.x;
    int wave = t >> 6;
    int lane = t & 63;
    int lo   = lane & 15;
    int quad = lane >> 4;
    int m0   = blockIdx.x * 64 + wave * 16;
    const short* ap = A + (size_t)(m0 + lo) * HC1 + quad * 8;

    f32x4 acc[17];
#pragma unroll
    for (int f = 0; f < 17; f++) acc[f] = (f32x4){0.f, 0.f, 0.f, 0.f};

    // stage tile k0=0
    for (int idx = t; idx < GCOLS * 4; idx += 256) {
        int c = idx >> 2, q = idx & 3;
        int s = (q + c + (c >> 2)) & 3;
        *(bf16x8*)(Bs + c * 32 + s * 8) = *(const bf16x8*)(W2X + (size_t)c * HC1 + q * 8);
    }
    __syncthreads();

#pragma unroll 1
    for (int k0 = 0; k0 < HC1; k0 += 32) {
        int nk = k0 + 32;
        bf16x8 pre[5];
        if (nk < HC1) {
#pragma unroll
            for (int j = 0; j < 5; j++) {
                int idx = t + j * 256;
                if (idx < GCOLS * 4) {
                    int c = idx >> 2, q = idx & 3;
                    pre[j] = *(const bf16x8*)(W2X + (size_t)c * HC1 + nk + q * 8);
                }
            }
        }
        bf16x8 aF = *(const bf16x8*)(ap + k0);
#pragma unroll
        for (int f = 0; f < 17; f++) {
            int c = f * 16 + lo;
            int s = (quad + c + (c >> 2)) & 3;
            bf16x8 bF = *(const bf16x8*)(Bs + c * 32 + s * 8);
            acc[f] = __builtin_amdgcn_mfma_f32_16x16x32_bf16(aF, bF, acc[f], 0, 0, 0);
        }
        __syncthreads();
        if (nk < HC1) {
#pragma unroll
            for (int j = 0; j < 5; j++) {
                int idx = t + j * 256;
                if (idx < GCOLS * 4) {
                    int c = idx >> 2, q = idx & 3;
                    int s = (q + c + (c >> 2)) & 3;
                    *(bf16x8*)(Bs + c * 32 + s * 8) = pre[j];
                }
            }
            __syncthreads();
        }
    }

    int rowb = m0 + quad * 4;
#pragma unroll
    for (int f = 0; f < 16; f++) {
#pragma unroll
        for (int r = 0; r < 4; r++) {
            int row = rowb + r;
            if (row < N_NODES)
                h2x[(size_t)row * H2S + f * 16 + lo] = f2bf(acc[f][r]);
        }
    }
#pragma unroll
    for (int r = 0; r < 4; r++) {
        int row = rowb + r;
        if (row < N_NODES) {
            if (lo < 8) *(float*)(h2x + (size_t)row * H2S + HC2 + 2 * lo) = acc[16][r];
            else        ed2[row * HEADS + (lo - 8)] = acc[16][r];
        }
    }
}

// -------- layer-2 GAT agg: at gather-service floor (control) -----------
// R8's hg fusion regressed 46->130us (serial shuffle chain); do not fuse.
__global__ __launch_bounds__(128) void k_gat_agg2(const ushort_t* __restrict__ h2x,
                                                  const float* __restrict__ ed2,
                                                  const int* __restrict__ offs,
                                                  const int2* __restrict__ csr,
                                                  const float* __restrict__ b2,
                                                  ushort_t* __restrict__ x3bf) {
    int wave = threadIdx.x >> 6;
    int lane = threadIdx.x & 63;
    int d = blockIdx.x * 2 + wave;
    if (d >= N_NODES) return;
    int c4 = lane * 4;            // 4 channels per lane
    int h  = lane >> 3;           // head = c4/32
    float edv = ed2[d * HEADS + h];
    int k0 = offs[d], k1 = offs[d + 1];
    float acc0 = 0.f, acc1 = 0.f, acc2 = 0.f, acc3 = 0.f, exsum = 0.f;
    int k = k0;
    for (; k + 3 < k1; k += 4) {
        int2 e0 = csr[k], e1 = csr[k + 1], e2 = csr[k + 2], e3 = csr[k + 3];
        const ushort_t* p0 = h2x + (size_t)e0.x * H2S;
        const ushort_t* p1 = h2x + (size_t)e1.x * H2S;
        const ushort_t* p2 = h2x + (size_t)e2.x * H2S;
        const ushort_t* p3 = h2x + (size_t)e3.x * H2S;
        float r0 = *(const float*)(p0 + HC2 + 2 * h);
        float r1 = *(const float*)(p1 + HC2 + 2 * h);
        float r2 = *(const float*)(p2 + HC2 + 2 * h);
        float r3 = *(const float*)(p3 + HC2 + 2 * h);
        ushort4 v0 = *(const ushort4*)(p0 + c4);
        ushort4 v1 = *(const ushort4*)(p1 + c4);
        ushort4 v2 = *(const ushort4*)(p2 + c4);
        ushort4 v3 = *(const ushort4*)(p3 + c4);
        float x0 = softnum(r0, edv);
        float x1 = softnum(r1, edv);
        float x2 = softnum(r2, edv);
        float x3 = softnum(r3, edv);
        acc0 += x0 * bf2f(v0.x) + x1 * bf2f(v1.x) + x2 * bf2f(v2.x) + x3 * bf2f(v3.x);
        acc1 += x0 * bf2f(v0.y) + x1 * bf2f(v1.y) + x2 * bf2f(v2.y) + x3 * bf2f(v3.y);
        acc2 += x0 * bf2f(v0.z) + x1 * bf2f(v1.z) + x2 * bf2f(v2.z) + x3 * bf2f(v3.z);
        acc3 += x0 * bf2f(v0.w) + x1 * bf2f(v1.w) + x2 * bf2f(v2.w) + x3 * bf2f(v3.w);
        exsum += (x0 + x1) + (x2 + x3);
    }
    for (; k < k1; k++) {
        int2 e0 = csr[k];
        const ushort_t* p0 = h2x + (size_t)e0.x * H2S;
        float x0 = softnum(*(const float*)(p0 + HC2 + 2 * h), edv);
        ushort4 v0 = *(const ushort4*)(p0 + c4);
        acc0 += x0 * bf2f(v0.x);
        acc1 += x0 * bf2f(v0.y);
        acc2 += x0 * bf2f(v0.z);
        acc3 += x0 * bf2f(v0.w);
        exsum += x0;
    }
    float inv = 1.f / (exsum + 1e-16f);
    float4 bias = *(const float4*)(b2 + c4);
    ushort4 o;
    o.x = f2bf(eluf(acc0 * inv + bias.x));
    o.y = f2bf(eluf(acc1 * inv + bias.y));
    o.z = f2bf(eluf(acc2 * inv + bias.z));
    o.w = f2bf(eluf(acc3 * inv + bias.w));
    *(ushort4*)(x3bf + (size_t)d * HC2 + c4) = o;
}

// ---------------- hg = x3 @ Wg  (N,256)@(256,16), bf16 x3 --------------
__global__ __launch_bounds__(256) void k_hg(const ushort_t* __restrict__ x3bf,
                                            const float* __restrict__ Wg,
                                            float* __restrict__ hg) {
    __shared__ float xs[16 * 260];
    int n0 = blockIdx.x * 16;
    int t  = threadIdx.x;
    for (int q = t; q < 16 * HC2 / 4; q += 256) {
        int r  = q >> 6;           // row within tile (64 ushort4 per row)
        int cc = (q & 63) * 4;
        int n  = n0 + r;
        ushort4 v = make_ushort4(0, 0, 0, 0);
        if (n < N_NODES) v = *(const ushort4*)(x3bf + (size_t)n * HC2 + cc);
        xs[r * 260 + cc + 0] = bf2f(v.x);
        xs[r * 260 + cc + 1] = bf2f(v.y);
        xs[r * 260 + cc + 2] = bf2f(v.z);
        xs[r * 260 + cc + 3] = bf2f(v.w);
    }
    __syncthreads();
    int r = t >> 4, c = t & 15;
    const float* xr = xs + r * 260;
    float acc = 0.f;
#pragma unroll 8
    for (int k = 0; k < HC2; k += 4) {
        float4 v = *(const float4*)(xr + k);
        acc += v.x * Wg[(k + 0) * C3 + c];
        acc += v.y * Wg[(k + 1) * C3 + c];
        acc += v.z * Wg[(k + 2) * C3 + c];
        acc += v.w * Wg[(k + 3) * C3 + c];
    }
    int n = n0 + r;
    if (n < N_NODES) hg[(size_t)n * C3 + c] = acc;
}

// ---------------- GCN aggregate + ELU + FC + sigmoid (fused) -----------
__global__ __launch_bounds__(256) void k_gcn_out(const float* __restrict__ hg,
                                                 const int* __restrict__ offs,
                                                 const int2* __restrict__ csr,
                                                 const float* __restrict__ bg,
                                                 const float* __restrict__ Wfc,
                                                 const float* __restrict__ bfc,
                                                 float* __restrict__ out) {
    int t = threadIdx.x;
    int r = t >> 4, c = t & 15;
    int d = blockIdx.x * 16 + r;
    float val = 0.f;
    if (d < N_NODES) {
        int k0 = offs[d], k1 = offs[d + 1];
        float acc = 0.f;
        int k = k0;
        for (; k + 3 < k1; k += 4) {
            int2 e0 = csr[k], e1 = csr[k + 1], e2 = csr[k + 2], e3 = csr[k + 3];
            float g0 = hg[(size_t)e0.x * C3 + c];
            float g1 = hg[(size_t)e1.x * C3 + c];
            float g2 = hg[(size_t)e2.x * C3 + c];
            float g3 = hg[(size_t)e3.x * C3 + c];
            acc += g0 * __int_as_float(e0.y) + g1 * __int_as_float(e1.y)
                 + g2 * __int_as_float(e2.y) + g3 * __int_as_float(e3.y);
        }
        for (; k < k1; k++) {
            int2 e0 = csr[k];
            acc += hg[(size_t)e0.x * C3 + c] * __int_as_float(e0.y);
        }
        val = eluf(acc + bg[c]);
    }
    float z = val * Wfc[c];
#pragma unroll
    for (int off = 8; off >= 1; off >>= 1) z += __shfl_xor(z, off, 16);
    if (c == 0 && d < N_NODES) out[d] = 1.f / (1.f + expf(-(z + bfc[0])));
}

// =======================================================================
extern "C" void kernel_launch(void* const* d_in, const int* in_sizes, int n_in,
                              void* d_out, int out_size, void* d_ws, size_t ws_size,
                              hipStream_t stream) {
    const float* x       = (const float*)d_in[0];
    const int*   ei      = (const int*)  d_in[1];
    const float* ew      = (const float*)d_in[2];
    const float* W1      = (const float*)d_in[3];
    const float* a_src1  = (const float*)d_in[4];
    const float* a_dst1  = (const float*)d_in[5];
    const float* b1      = (const float*)d_in[6];
    const float* W2      = (const float*)d_in[7];
    const float* a_src2  = (const float*)d_in[8];
    const float* a_dst2  = (const float*)d_in[9];
    const float* b2      = (const float*)d_in[10];
    const float* Wg      = (const float*)d_in[11];
    const float* bg      = (const float*)d_in[12];
    const float* Wfc     = (const float*)d_in[13];
    const float* bfc     = (const float*)d_in[14];
    float* out = (float*)d_out;

    char* w = (char*)d_ws;
    size_t off = 0;
    auto alloc = [&](size_t bytes) -> void* {
        void* p = w + off;
        off = (off + bytes + 255) & ~(size_t)255;
        return p;
    };
    ushort_t* x2bf = (ushort_t*)alloc((size_t)MPAD * HC1 * 2);
    ushort_t* W2X  = (ushort_t*)alloc((size_t)GCOLS * HC1 * 2);
    ushort_t* h2x  = (ushort_t*)alloc((size_t)N_NODES * H2S * 2);
    ushort_t* x3bf = (ushort_t*)alloc((size_t)N_NODES * HC2 * 2);
    float* hg     = (float*)alloc((size_t)N_NODES * C3 * 4);
    float* es1    = (float*)alloc((size_t)NH8 * 4);
    float* ed1    = (float*)alloc((size_t)NH8 * 4);
    float* ed2    = (float*)alloc((size_t)NH8 * 4);
    // zero-init region: just the u64 degree pack
    unsigned long long* pack = (unsigned long long*)alloc((size_t)N_NODES * 8);
    char*  zero_end = w + off;
    ushort_t* rank = (ushort_t*)alloc((size_t)N_EDGES * 2);
    int*   offs   = (int*)  alloc((size_t)(N_NODES + 1) * 4);
    int*   part   = (int*)  alloc(256 * 4);
    int2*  csr    = (int2*) alloc((size_t)ETOT * 8);
    float* dinv   = (float*)alloc((size_t)N_NODES * 4);
    float* xp8    = (float*)alloc((size_t)N_NODES * 8 * 4);

    // ---- CSR build + init + weight prep ----
    hipMemsetAsync(pack, 0, (size_t)(zero_end - (char*)pack), stream);
    k_init<<<dim3(INIT_TOT), dim3(256), 0, stream>>>(
        ei, ew, pack, rank, x, xp8, W2, a_src2, a_dst2, W2X,
        W1, a_src1, a_dst1, es1, ed1);
    k_scan_a<<<dim3(NCHUNK), dim3(256), 0, stream>>>(pack, part);
    k_scan_c<<<dim3(NCHUNK), dim3(256), 0, stream>>>(pack, part, offs, dinv);
    k_scatter<<<dim3(SCATBLK), dim3(256), 0, stream>>>(ei, offs, rank, csr, ew, dinv);

    // ---- GAT layer 1 (agg + expand fused via LDS) ----
    k_aggexp<<<dim3(ES1BLK), dim3(256), 0, stream>>>(
        xp8, es1, ed1, offs, csr, W1, b1, x2bf);

    // ---- GAT layer 2 (GEMM emits h2 rows with es tail + ed2) ----
    k_gemm_mfma<<<dim3(MPAD / 64), dim3(256), 0, stream>>>(
        (const short*)x2bf, (const short*)W2X, h2x, ed2);
    k_gat_agg2<<<dim3((N_NODES + 1) / 2), dim3(128), 0, stream>>>(
        h2x, ed2, offs, csr, b2, x3bf);

    // ---- GCN + FC + sigmoid ----
    k_hg<<<dim3((N_NODES + 15) / 16), dim3(256), 0, stream>>>(x3bf, Wg, hg);
    k_gcn_out<<<dim3((N_NODES + 15) / 16), dim3(256), 0, stream>>>(
        hg, offs, csr, bg, Wfc, bfc, out);
}